// Round 10
// baseline (241.370 us; speedup 1.0000x reference)
//
#include <hip/hip_runtime.h>
#include <math.h>

#define DIN 1024
#define DH 512
#define DATT 256
#define CNUM 10
#define NCLS 4
#define NH 64              // histogram blocks
#define NSC 40             // scatter blocks

typedef __attribute__((ext_vector_type(8))) short bf16x8;
typedef __attribute__((ext_vector_type(4))) float f32x4;
typedef unsigned short ushort_t;
typedef unsigned int uint_t;

__device__ inline ushort_t f2bf(float f) {
    uint_t u = __float_as_uint(f);
    u += 0x7FFF + ((u >> 16) & 1);   // RNE
    return (ushort_t)(u >> 16);
}

// async global->LDS, 16B per lane. LDS dst must be wave-uniform base + lane*16.
// Global src may be any per-lane address.
__device__ inline void gl_lds16(const void* g, void* l) {
    __builtin_amdgcn_global_load_lds(
        (const __attribute__((address_space(1))) unsigned int*)g,
        (__attribute__((address_space(3))) unsigned int*)l, 16, 0, 0);
}

// ---------------- dispatch 1: histogram + init (cid-only deps) ----------------

__global__ __launch_bounds__(256) void k_hist(
    const int* __restrict__ cid, int n, const float* __restrict__ bc,
    int* __restrict__ counts_part, float* __restrict__ pooled,
    float* __restrict__ a_logit, int* __restrict__ scat_pos)
{
    int bid = blockIdx.x;
    int t = threadIdx.x;

    if (bid < NH) {
        __shared__ int h[CNUM];
        int lane = t & 63;
        if (t < CNUM) h[t] = 0;
        __syncthreads();
        for (int i = bid * 256 + t; i < n; i += NH * 256) {
            int c = cid[i];
            #pragma unroll
            for (int cc = 0; cc < CNUM; cc++) {
                unsigned long long mask = __ballot(c == cc);
                if (mask == 0ull) continue;
                if (lane == (__ffsll(mask) - 1)) atomicAdd(&h[cc], __popcll(mask));
            }
        }
        __syncthreads();
        if (t < CNUM) counts_part[bid * 16 + t] = h[t];
        return;
    }

    // init block
    for (int i = t; i < CNUM * DH; i += 256) pooled[i] = 0.f;
    if (t < CNUM) a_logit[t] = bc[0];
    if (t < CNUM) scat_pos[t] = 0;
}

// ---------------- dispatch 2: scatter (first) + casts (independent) ----------------

__global__ __launch_bounds__(256) void k_scat2(
    const int* __restrict__ cid, int n, const int* __restrict__ counts_part,
    const float* __restrict__ x, const float* __restrict__ W1, const float* __restrict__ W2,
    ushort_t* __restrict__ xb, ushort_t* __restrict__ W1t, ushort_t* __restrict__ W2t,
    int nxb, int nw,
    int* __restrict__ counts, int* __restrict__ offsets, int* __restrict__ tile_off,
    int* __restrict__ scat_pos, int* __restrict__ bucket)
{
    int bid = blockIdx.x;
    int t = threadIdx.x;

    if (bid < NSC) {
        __shared__ int cnts[CNUM], off[CNUM];
        if (t < CNUM) {
            int s = 0;
            #pragma unroll 8
            for (int b = 0; b < NH; b++) s += counts_part[b * 16 + t];
            cnts[t] = s;
        }
        __syncthreads();
        if (t == 0) {
            int a = 0;
            for (int c = 0; c < CNUM; c++) { off[c] = a; a += cnts[c]; }
            if (bid == 0) {
                int aa = 0, tt = 0;
                for (int c = 0; c < CNUM; c++) {
                    offsets[c] = aa; tile_off[c] = tt; counts[c] = cnts[c];
                    aa += cnts[c]; tt += (cnts[c] + 255) >> 8;   // 256-row tiles
                }
                offsets[CNUM] = aa; tile_off[CNUM] = tt;
            }
        }
        __syncthreads();
        int lane = t & 63;
        for (int i = bid * 256 + t; i < n; i += NSC * 256) {
            int c = cid[i];
            #pragma unroll
            for (int cc = 0; cc < CNUM; cc++) {
                unsigned long long mask = __ballot(c == cc);
                if (mask == 0ull) continue;
                int leader = __ffsll(mask) - 1;
                int basep = 0;
                if (lane == leader) basep = atomicAdd(&scat_pos[cc], __popcll(mask));
                basep = __shfl(basep, leader, 64);
                if (c == cc) {
                    int rank = __popcll(mask & ((1ull << lane) - 1ull));
                    bucket[off[cc] + basep + rank] = i;
                }
            }
        }
        return;
    }
    bid -= NSC;

    if (bid < nxb) {
        int row = bid * 2 + (t >> 7);
        if (row >= n) return;
        int col = (t & 127) * 8;
        const float* src = x + (size_t)row * DIN + col;
        float4 v0 = *(const float4*)(src);
        float4 v1 = *(const float4*)(src + 4);
        ushort_t* dst = xb + (size_t)row * DIN + col;
        *(ushort4*)dst = make_ushort4(f2bf(v0.x), f2bf(v0.y), f2bf(v0.z), f2bf(v0.w));
        *(ushort4*)(dst + 4) = make_ushort4(f2bf(v1.x), f2bf(v1.y), f2bf(v1.z), f2bf(v1.w));
        return;
    }
    bid -= nxb;

    if (bid < nw) {
        __shared__ float tile[64][65];
        int z = bid >> 7;
        int kx = (bid & 127) >> 3;
        int ny = bid & 7;
        const float* src; ushort_t* dst; int K;
        if (z < CNUM) { K = DIN; src = W1 + (size_t)z * K * DH; dst = W1t + (size_t)z * DH * K; }
        else          { K = DH;  src = W2 + (size_t)(z - CNUM) * K * DH; dst = W2t + (size_t)(z - CNUM) * DH * K; }
        int k0 = kx * 64;
        if (k0 >= K) return;
        int n0 = ny * 64;
        int rr = t >> 4;
        int cc = (t & 15) * 4;
        #pragma unroll
        for (int i = 0; i < 4; i++) {
            int row = rr + 16 * i;
            float4 v = *(const float4*)(src + (size_t)(k0 + row) * DH + n0 + cc);
            tile[row][cc + 0] = v.x; tile[row][cc + 1] = v.y;
            tile[row][cc + 2] = v.z; tile[row][cc + 3] = v.w;
        }
        __syncthreads();
        #pragma unroll
        for (int i = 0; i < 4; i++) {
            int nrow = rr + 16 * i;
            ushort4 o = make_ushort4(f2bf(tile[cc + 0][nrow]), f2bf(tile[cc + 1][nrow]),
                                     f2bf(tile[cc + 2][nrow]), f2bf(tile[cc + 3][nrow]));
            *(ushort4*)(dst + (size_t)(n0 + nrow) * K + k0 + cc) = o;
        }
    }
}

// ---------------- grouped GEMM, 256x64 tile, BK=32 ----------------
// grid (8, maxt): x = n-tile. Block = 4 waves; wave w owns rows 64w..64w+63, all
// waves share the 64-col B tile. Per K-step: 5x gl_lds16 (20 KB) for 64 MFMA.
// A frag: lane reads As[64w+16mf+m][quad*8..+7]; C/D: col=lane&15, row=quad*4+reg.

__device__ inline void gemm_tile256(
    const ushort_t* aSrc0, const ushort_t* aSrc1,
    const ushort_t* aSrc2, const ushort_t* aSrc3,
    const ushort_t* bSrc, int Kd,
    f32x4 acc[4][4], ushort_t As[256][32], ushort_t Bs[64][32])
{
    int t = threadIdx.x;
    int lane = t & 63;
    int w = t >> 6;
    int m = lane & 15, quad = lane >> 4;

    int r0 = t >> 2;
    int kc = (t & 3) * 8;

    ushort_t* aDst0 = &As[r0][kc];
    ushort_t* aDst1 = &As[64 + r0][kc];
    ushort_t* aDst2 = &As[128 + r0][kc];
    ushort_t* aDst3 = &As[192 + r0][kc];
    ushort_t* bDst  = &Bs[r0][kc];

    const ushort_t* aF = &As[64 * w + m][quad * 8];
    const ushort_t* bF = &Bs[m][quad * 8];

    for (int k0 = 0; k0 < Kd; k0 += 32) {
        __syncthreads();
        gl_lds16(aSrc0 + k0, aDst0);
        gl_lds16(aSrc1 + k0, aDst1);
        gl_lds16(aSrc2 + k0, aDst2);
        gl_lds16(aSrc3 + k0, aDst3);
        gl_lds16(bSrc + k0, bDst);
        __syncthreads();
        bf16x8 a[4], b[4];
        #pragma unroll
        for (int mf = 0; mf < 4; mf++) a[mf] = *(const bf16x8*)(aF + mf * 16 * 32);
        #pragma unroll
        for (int nf = 0; nf < 4; nf++) b[nf] = *(const bf16x8*)(bF + nf * 16 * 32);
        #pragma unroll
        for (int mf = 0; mf < 4; mf++)
            #pragma unroll
            for (int nf = 0; nf < 4; nf++)
                acc[mf][nf] = __builtin_amdgcn_mfma_f32_16x16x32_bf16(a[mf], b[nf], acc[mf][nf], 0, 0, 0);
    }
}

__global__ __launch_bounds__(256, 1) void k_mfma1(
    const ushort_t* __restrict__ xb, const ushort_t* __restrict__ W1t,
    const float* __restrict__ b1, const int* __restrict__ bucket,
    const int* __restrict__ offsets, const int* __restrict__ counts,
    const int* __restrict__ tile_off,
    ushort_t* __restrict__ H1)
{
    __shared__ ushort_t As[256][32];
    __shared__ ushort_t Bs[64][32];
    int tx = blockIdx.y;
    if (tx >= tile_off[CNUM]) return;
    int c = 0;
    while (tx >= tile_off[c + 1]) c++;
    int m0 = (tx - tile_off[c]) * 256;
    int base = offsets[c], cnt = counts[c];
    int tile_n = blockIdx.x * 64;

    int t = threadIdx.x;
    int r0 = t >> 2;
    int kc = (t & 3) * 8;
    const ushort_t* aS[4];
    #pragma unroll
    for (int i = 0; i < 4; i++) {
        int ra = m0 + 64 * i + r0;
        if (ra > cnt - 1) ra = cnt - 1;
        aS[i] = xb + (size_t)bucket[base + ra] * DIN + kc;   // indirect gather
    }
    const ushort_t* bSrc = W1t + ((size_t)c * DH + tile_n + r0) * DIN + kc;

    f32x4 acc[4][4] = {};
    gemm_tile256(aS[0], aS[1], aS[2], aS[3], bSrc, DIN, acc, As, Bs);

    int lane = t & 63;
    int w = t >> 6;
    int m = lane & 15, quad = lane >> 4;
    #pragma unroll
    for (int nf = 0; nf < 4; nf++) {
        int col = tile_n + 16 * nf + m;
        float bv = b1[c * DH + col];
        #pragma unroll
        for (int mf = 0; mf < 4; mf++) {
            int rowb = m0 + 64 * w + 16 * mf + quad * 4;
            #pragma unroll
            for (int r = 0; r < 4; r++) {
                int row = rowb + r;
                if (row < cnt)
                    H1[(size_t)(base + row) * DH + col] = f2bf(fmaxf(acc[mf][nf][r] + bv, 0.f));
            }
        }
    }
}

__global__ __launch_bounds__(256, 1) void k_mfma2(
    const ushort_t* __restrict__ H1, const ushort_t* __restrict__ W2t,
    const float* __restrict__ b2,
    const int* __restrict__ offsets, const int* __restrict__ counts,
    const int* __restrict__ tile_off,
    float* __restrict__ pooled)
{
    __shared__ ushort_t As[256][32];
    __shared__ ushort_t Bs[64][32];
    __shared__ float red2[4][64];
    int tx = blockIdx.y;
    if (tx >= tile_off[CNUM]) return;
    int c = 0;
    while (tx >= tile_off[c + 1]) c++;
    int m0 = (tx - tile_off[c]) * 256;
    int base = offsets[c], cnt = counts[c];
    int tile_n = blockIdx.x * 64;

    int t = threadIdx.x;
    int r0 = t >> 2;
    int kc = (t & 3) * 8;
    const ushort_t* aS[4];
    #pragma unroll
    for (int i = 0; i < 4; i++) {
        int ra = m0 + 64 * i + r0;
        if (ra > cnt - 1) ra = cnt - 1;
        aS[i] = H1 + (size_t)(base + ra) * DH + kc;
    }
    const ushort_t* bSrc = W2t + ((size_t)c * DH + tile_n + r0) * DH + kc;

    f32x4 acc[4][4] = {};
    gemm_tile256(aS[0], aS[1], aS[2], aS[3], bSrc, DH, acc, As, Bs);

    int lane = t & 63;
    int w = t >> 6;
    int m = lane & 15, quad = lane >> 4;
    // per-wave masked column sums, then block-level LDS reduce -> 1 atomic/col
    #pragma unroll
    for (int nf = 0; nf < 4; nf++) {
        int col = tile_n + 16 * nf + m;
        float bv = b2[c * DH + col];
        float s = 0.f;
        #pragma unroll
        for (int mf = 0; mf < 4; mf++) {
            int rowb = m0 + 64 * w + 16 * mf + quad * 4;
            #pragma unroll
            for (int r = 0; r < 4; r++) {
                int row = rowb + r;
                if (row < cnt) s += fmaxf(acc[mf][nf][r] + bv, 0.f);
            }
        }
        s += __shfl_xor(s, 16);
        s += __shfl_xor(s, 32);
        if (quad == 0) red2[w][16 * nf + m] = s;
    }
    __syncthreads();
    if (t < 64) {
        float s = red2[0][t] + red2[1][t] + red2[2][t] + red2[3][t];
        atomicAdd(&pooled[c * DH + tile_n + t], s);
    }
}

// ---------------- parallel epilogue (R7-proven split tail) ----------------

__global__ __launch_bounds__(256) void k_fc2(
    const float* __restrict__ pooled, const int* __restrict__ counts,
    const float* __restrict__ Wfc, const float* __restrict__ bfc,
    float* __restrict__ hfc)
{
    int c = blockIdx.x;
    int c0 = blockIdx.y * 64;
    __shared__ float ps[DH];
    __shared__ float red[4][64];
    int t = threadIdx.x;
    float cnt = fmaxf((float)counts[c], 1.f);
    ps[t] = pooled[c * DH + t] / cnt;
    ps[t + 256] = pooled[c * DH + t + 256] / cnt;
    __syncthreads();
    int col = c0 + (t & 63);
    int ks = t >> 6;
    float acc = 0.f;
    #pragma unroll 8
    for (int k = ks * 128; k < ks * 128 + 128; k++)
        acc = fmaf(ps[k], Wfc[(size_t)k * DH + col], acc);
    red[ks][t & 63] = acc;
    __syncthreads();
    if (t < 64) {
        float v = red[0][t] + red[1][t] + red[2][t] + red[3][t] + bfc[c0 + t];
        hfc[c * DH + c0 + t] = fmaxf(v, 0.f);
    }
}

__global__ __launch_bounds__(256) void k_gate2(
    const float* __restrict__ hfc,
    const float* __restrict__ Wa, const float* __restrict__ ba,
    const float* __restrict__ Wb, const float* __restrict__ bb,
    const float* __restrict__ Wc,
    float* __restrict__ a_logit)
{
    int c = blockIdx.x;
    int d0 = blockIdx.y * 64;
    __shared__ float hf[DH];
    __shared__ float ra[4][64], rb[4][64];
    int t = threadIdx.x;
    hf[t] = hfc[c * DH + t];
    hf[t + 256] = hfc[c * DH + t + 256];
    __syncthreads();
    int d = d0 + (t & 63);
    int ks = t >> 6;
    float ga = 0.f, gb = 0.f;
    #pragma unroll 8
    for (int k = ks * 128; k < ks * 128 + 128; k++) {
        float h = hf[k];
        ga = fmaf(h, Wa[(size_t)k * DATT + d], ga);
        gb = fmaf(h, Wb[(size_t)k * DATT + d], gb);
    }
    ra[ks][t & 63] = ga;
    rb[ks][t & 63] = gb;
    __syncthreads();
    if (t < 64) {
        float sa = ra[0][t] + ra[1][t] + ra[2][t] + ra[3][t] + ba[d0 + t];
        float sb = rb[0][t] + rb[1][t] + rb[2][t] + rb[3][t] + bb[d0 + t];
        float g = tanhf(sa) * (1.f / (1.f + expf(-sb)));
        float p = g * Wc[d0 + t];
        #pragma unroll
        for (int off = 32; off >= 1; off >>= 1) p += __shfl_down(p, off, 64);
        if (t == 0) atomicAdd(&a_logit[c], p);
    }
}

__global__ __launch_bounds__(1024) void k_final(
    const float* __restrict__ hfc, const float* __restrict__ a_logit,
    const float* __restrict__ Wr, const float* __restrict__ br,
    const float* __restrict__ Wcls, const float* __restrict__ bcls,
    float* __restrict__ out)
{
    int t = threadIdx.x;
    __shared__ float hp[DH];
    __shared__ float r1[4][DATT];
    __shared__ float hr[DATT];
    __shared__ float wred[4][NCLS];

    float al[CNUM];
    float m = -1e30f;
    #pragma unroll
    for (int c = 0; c < CNUM; c++) { al[c] = a_logit[c]; m = fmaxf(m, al[c]); }
    float s = 0.f;
    #pragma unroll
    for (int c = 0; c < CNUM; c++) { al[c] = expf(al[c] - m); s += al[c]; }
    float inv = 1.f / s;

    if (t < DH) {
        float v = 0.f;
        #pragma unroll
        for (int c = 0; c < CNUM; c++) v = fmaf(al[c] * inv, hfc[c * DH + t], v);
        hp[t] = v;
    }
    __syncthreads();

    int d = t & 255;
    int ks = t >> 8;
    float acc = 0.f;
    #pragma unroll 8
    for (int k = ks * 128; k < ks * 128 + 128; k++)
        acc = fmaf(hp[k], Wr[(size_t)k * DATT + d], acc);
    r1[ks][d] = acc;
    __syncthreads();
    if (t < DATT)
        hr[t] = fmaxf(r1[0][t] + r1[1][t] + r1[2][t] + r1[3][t] + br[t], 0.f);
    __syncthreads();

    if (t < 256) {
        float h = hr[t];
        #pragma unroll
        for (int cls = 0; cls < NCLS; cls++) {
            float p = h * Wcls[(size_t)t * NCLS + cls];
            #pragma unroll
            for (int off = 32; off >= 1; off >>= 1) p += __shfl_down(p, off, 64);
            if ((t & 63) == 0) wred[t >> 6][cls] = p;
        }
    }
    __syncthreads();
    if (t == 0) {
        float lg[NCLS];
        #pragma unroll
        for (int cls = 0; cls < NCLS; cls++)
            lg[cls] = bcls[cls] + wred[0][cls] + wred[1][cls] + wred[2][cls] + wred[3][cls];
        float mm = lg[0];
        #pragma unroll
        for (int i = 1; i < NCLS; i++) mm = fmaxf(mm, lg[i]);
        float ss = 0.f, pr[NCLS];
        #pragma unroll
        for (int i = 0; i < NCLS; i++) { pr[i] = expf(lg[i] - mm); ss += pr[i]; }
        int am = 0; float best = lg[0];
        #pragma unroll
        for (int i = 1; i < NCLS; i++) if (lg[i] > best) { best = lg[i]; am = i; }
        #pragma unroll
        for (int i = 0; i < NCLS; i++) out[i] = lg[i];
        #pragma unroll
        for (int i = 0; i < NCLS; i++) out[4 + i] = pr[i] / ss;
        out[8] = (float)am;
    }
}

// ---------------- fp32 fallback GEMMs (round-1 proven) ----------------

#define MT 64
#define NT 128
#define KT 32

__global__ __launch_bounds__(256) void k_gemm1(
    const float* __restrict__ x, const float* __restrict__ W1, const float* __restrict__ b1,
    const int* __restrict__ bucket, const int* __restrict__ offsets, const int* __restrict__ counts,
    float* __restrict__ H1)
{
    int c = blockIdx.z;
    int cnt = counts[c];
    int m0 = blockIdx.x * MT;
    if (m0 >= cnt) return;
    int rows = min(MT, cnt - m0);
    int n0 = blockIdx.y * NT;
    int base = offsets[c];

    __shared__ float As[KT][MT + 4];
    __shared__ float Bs[KT][NT];

    int t = threadIdx.x;
    int tr = t >> 4;
    int tc = t & 15;
    int lr = t >> 2;
    int lk = (t & 3) * 8;
    const float* xrow = nullptr;
    if (lr < rows) xrow = x + (size_t)bucket[base + m0 + lr] * DIN;

    float acc[4][8];
    #pragma unroll
    for (int i = 0; i < 4; i++)
        #pragma unroll
        for (int j = 0; j < 8; j++) acc[i][j] = 0.f;

    const float* Wp = W1 + (size_t)c * DIN * DH + n0;

    for (int k0 = 0; k0 < DIN; k0 += KT) {
        __syncthreads();
        if (xrow) {
            float4 v0 = *(const float4*)(xrow + k0 + lk);
            float4 v1 = *(const float4*)(xrow + k0 + lk + 4);
            As[lk + 0][lr] = v0.x; As[lk + 1][lr] = v0.y;
            As[lk + 2][lr] = v0.z; As[lk + 3][lr] = v0.w;
            As[lk + 4][lr] = v1.x; As[lk + 5][lr] = v1.y;
            As[lk + 6][lr] = v1.z; As[lk + 7][lr] = v1.w;
        } else {
            #pragma unroll
            for (int i = 0; i < 8; i++) As[lk + i][lr] = 0.f;
        }
        #pragma unroll
        for (int i = 0; i < 4; i++) {
            int idx = i * 256 + t;
            int kk = idx >> 5;
            int cv = idx & 31;
            *(float4*)&Bs[kk][cv * 4] = *(const float4*)(Wp + (size_t)(k0 + kk) * DH + cv * 4);
        }
        __syncthreads();
        #pragma unroll
        for (int k = 0; k < KT; k++) {
            float4 av  = *(const float4*)&As[k][4 * tr];
            float4 bv0 = *(const float4*)&Bs[k][4 * tc];
            float4 bv1 = *(const float4*)&Bs[k][64 + 4 * tc];
            float a[4] = {av.x, av.y, av.z, av.w};
            float b[8] = {bv0.x, bv0.y, bv0.z, bv0.w, bv1.x, bv1.y, bv1.z, bv1.w};
            #pragma unroll
            for (int i = 0; i < 4; i++)
                #pragma unroll
                for (int j = 0; j < 8; j++)
                    acc[i][j] = fmaf(a[i], b[j], acc[i][j]);
        }
    }

    #pragma unroll
    for (int i = 0; i < 4; i++) {
        int r = 4 * tr + i;
        if (r < rows) {
            size_t grow = (size_t)(base + m0 + r) * DH;
            #pragma unroll
            for (int j = 0; j < 8; j++) {
                int cidx = (j < 4) ? (4 * tc + j) : (64 + 4 * tc + (j - 4));
                int col = n0 + cidx;
                float v = acc[i][j] + b1[c * DH + col];
                H1[grow + col] = fmaxf(v, 0.f);
            }
        }
    }
}

__global__ __launch_bounds__(256) void k_gemm2(
    const float* __restrict__ H1, const float* __restrict__ W2, const float* __restrict__ b2,
    const int* __restrict__ offsets, const int* __restrict__ counts,
    float* __restrict__ pooled)
{
    int c = blockIdx.z;
    int cnt = counts[c];
    int m0 = blockIdx.x * MT;
    if (m0 >= cnt) return;
    int rows = min(MT, cnt - m0);
    int n0 = blockIdx.y * NT;
    int base = offsets[c];

    __shared__ float As[KT][MT + 4];
    __shared__ float Bs[KT][NT];
    __shared__ float red[16][NT];

    int t = threadIdx.x;
    int tr = t >> 4;
    int tc = t & 15;
    int lr = t >> 2;
    int lk = (t & 3) * 8;
    const float* arow = (lr < rows) ? (H1 + (size_t)(base + m0 + lr) * DH) : nullptr;

    float acc[4][8];
    #pragma unroll
    for (int i = 0; i < 4; i++)
        #pragma unroll
        for (int j = 0; j < 8; j++) acc[i][j] = 0.f;

    const float* Wp = W2 + (size_t)c * DH * DH + n0;

    for (int k0 = 0; k0 < DH; k0 += KT) {
        __syncthreads();
        if (arow) {
            float4 v0 = *(const float4*)(arow + k0 + lk);
            float4 v1 = *(const float4*)(arow + k0 + lk + 4);
            As[lk + 0][lr] = v0.x; As[lk + 1][lr] = v0.y;
            As[lk + 2][lr] = v0.z; As[lk + 3][lr] = v0.w;
            As[lk + 4][lr] = v1.x; As[lk + 5][lr] = v1.y;
            As[lk + 6][lr] = v1.z; As[lk + 7][lr] = v1.w;
        } else {
            #pragma unroll
            for (int i = 0; i < 8; i++) As[lk + i][lr] = 0.f;
        }
        #pragma unroll
        for (int i = 0; i < 4; i++) {
            int idx = i * 256 + t;
            int kk = idx >> 5;
            int cv = idx & 31;
            *(float4*)&Bs[kk][cv * 4] = *(const float4*)(Wp + (size_t)(k0 + kk) * DH + cv * 4);
        }
        __syncthreads();
        #pragma unroll
        for (int k = 0; k < KT; k++) {
            float4 av  = *(const float4*)&As[k][4 * tr];
            float4 bv0 = *(const float4*)&Bs[k][4 * tc];
            float4 bv1 = *(const float4*)&Bs[k][64 + 4 * tc];
            float a[4] = {av.x, av.y, av.z, av.w};
            float b[8] = {bv0.x, bv0.y, bv0.z, bv0.w, bv1.x, bv1.y, bv1.z, bv1.w};
            #pragma unroll
            for (int i = 0; i < 4; i++)
                #pragma unroll
                for (int j = 0; j < 8; j++)
                    acc[i][j] = fmaf(a[i], b[j], acc[i][j]);
        }
    }

    __syncthreads();
    #pragma unroll
    for (int j = 0; j < 8; j++) {
        int cidx = (j < 4) ? (4 * tc + j) : (64 + 4 * tc + (j - 4));
        float bias = b2[c * DH + n0 + cidx];
        float s = 0.f;
        #pragma unroll
        for (int i = 0; i < 4; i++) {
            if (4 * tr + i < rows) s += fmaxf(acc[i][j] + bias, 0.f);
        }
        red[tr][cidx] = s;
    }
    __syncthreads();
    if (t < NT) {
        float s = 0.f;
        #pragma unroll
        for (int r = 0; r < 16; r++) s += red[r][t];
        atomicAdd(&pooled[c * DH + n0 + t], s);
    }
}

// ---------------- launcher ----------------

extern "C" void kernel_launch(void* const* d_in, const int* in_sizes, int n_in,
                              void* d_out, int out_size, void* d_ws, size_t ws_size,
                              hipStream_t stream) {
    (void)n_in; (void)out_size;
    const float* x    = (const float*)d_in[0];
    const int*   cid  = (const int*)d_in[1];
    const float* W1   = (const float*)d_in[2];
    const float* b1   = (const float*)d_in[3];
    const float* W2   = (const float*)d_in[4];
    const float* b2   = (const float*)d_in[5];
    const float* Wfc  = (const float*)d_in[6];
    const float* bfc  = (const float*)d_in[7];
    const float* Wa   = (const float*)d_in[8];
    const float* ba   = (const float*)d_in[9];
    const float* Wb   = (const float*)d_in[10];
    const float* bb   = (const float*)d_in[11];
    const float* Wc   = (const float*)d_in[12];
    const float* bc   = (const float*)d_in[13];
    const float* Wr   = (const float*)d_in[14];
    const float* br   = (const float*)d_in[15];
    const float* Wcls = (const float*)d_in[16];
    const float* bcls = (const float*)d_in[17];
    float* out = (float*)d_out;
    float* ws  = (float*)d_ws;

    int n = in_sizes[1];

    float* pooled     = ws + 0;                  // 5120
    int*   counts     = (int*)(ws + 5120);       // 16
    int*   offsets    = (int*)(ws + 5136);       // 16
    int*   tile_off   = (int*)(ws + 5152);       // 16
    float* a_logit    = ws + 5168;               // 16
    int*   scat_pos   = (int*)(ws + 5184);       // 16
    float* hfc        = ws + 5200;               // 5120 -> 10320
    int*   counts_part= (int*)(ws + 10320);      // 1024 -> 11344
    int*   bucket     = (int*)(ws + 11344);      // n

    size_t big0 = (((size_t)(11344 + n) * 4) + 255) & ~(size_t)255;
    size_t w1t_bytes = (size_t)CNUM * DH * DIN * 2;
    size_t w2t_bytes = (size_t)CNUM * DH * DH * 2;
    size_t h1_bytes  = (size_t)n * DH * 2;
    size_t xb_bytes  = (size_t)n * DIN * 2;
    size_t need = big0 + w1t_bytes + w2t_bytes + h1_bytes + xb_bytes;

    ushort_t* W1t = (ushort_t*)((char*)d_ws + big0);
    ushort_t* W2t = (ushort_t*)((char*)d_ws + big0 + w1t_bytes);
    ushort_t* H1  = (ushort_t*)((char*)d_ws + big0 + w1t_bytes + w2t_bytes);
    ushort_t* xb  = (ushort_t*)((char*)d_ws + big0 + w1t_bytes + w2t_bytes + h1_bytes);

    int fast = (ws_size >= need) ? 1 : 0;
    int nxb = fast ? (n + 1) / 2 : 0;
    int nw  = fast ? 128 * 2 * CNUM : 0;

    k_hist<<<NH + 1, 256, 0, stream>>>(cid, n, bc, counts_part, pooled, a_logit, scat_pos);
    k_scat2<<<NSC + nxb + nw, 256, 0, stream>>>(
        cid, n, counts_part, x, W1, W2, xb, W1t, W2t, nxb, nw,
        counts, offsets, tile_off, scat_pos, bucket);

    if (fast) {
        int maxt = n / 256 + CNUM;
        k_mfma1<<<dim3(8, maxt), 256, 0, stream>>>(xb, W1t, b1, bucket, offsets, counts, tile_off, H1);
        k_mfma2<<<dim3(8, maxt), 256, 0, stream>>>(H1, W2t, b2, offsets, counts, tile_off, pooled);
    } else {
        float* H1f = ws + ((11344 + n + 31) & ~31);
        dim3 gg((n + MT - 1) / MT, DH / NT, CNUM);
        k_gemm1<<<gg, 256, 0, stream>>>(x, W1, b1, bucket, offsets, counts, H1f);
        k_gemm2<<<gg, 256, 0, stream>>>(H1f, W2, b2, offsets, counts, pooled);
    }

    k_fc2<<<dim3(CNUM, 8), 256, 0, stream>>>(pooled, counts, Wfc, bfc, hfc);
    k_gate2<<<dim3(CNUM, 4), 256, 0, stream>>>(hfc, Wa, ba, Wb, bb, Wc, a_logit);
    k_final<<<1, 1024, 0, stream>>>(hfc, a_logit, Wr, br, Wcls, bcls, out);
}

// Round 11
// 230.279 us; speedup vs baseline: 1.0482x; 1.0482x over previous
//
#include <hip/hip_runtime.h>
#include <math.h>

#define DIN 1024
#define DH 512
#define DATT 256
#define CNUM 10
#define NCLS 4
#define NH 64              // histogram blocks
#define NSC 40             // scatter blocks

typedef __attribute__((ext_vector_type(8))) short bf16x8;
typedef __attribute__((ext_vector_type(4))) float f32x4;
typedef unsigned short ushort_t;
typedef unsigned int uint_t;

__device__ inline ushort_t f2bf(float f) {
    uint_t u = __float_as_uint(f);
    u += 0x7FFF + ((u >> 16) & 1);   // RNE
    return (ushort_t)(u >> 16);
}

// async global->LDS, 16B per lane. LDS dst must be wave-uniform base + lane*16.
__device__ inline void gl_lds16(const void* g, void* l) {
    __builtin_amdgcn_global_load_lds(
        (const __attribute__((address_space(1))) unsigned int*)g,
        (__attribute__((address_space(3))) unsigned int*)l, 16, 0, 0);
}

// ---------------- dispatch 1: histogram + init (cid-only deps) ----------------

__global__ __launch_bounds__(256) void k_hist(
    const int* __restrict__ cid, int n, const float* __restrict__ bc,
    int* __restrict__ counts_part, float* __restrict__ pooled,
    float* __restrict__ a_logit, int* __restrict__ scat_pos)
{
    int bid = blockIdx.x;
    int t = threadIdx.x;

    if (bid < NH) {
        __shared__ int h[CNUM];
        int lane = t & 63;
        if (t < CNUM) h[t] = 0;
        __syncthreads();
        for (int i = bid * 256 + t; i < n; i += NH * 256) {
            int c = cid[i];
            #pragma unroll
            for (int cc = 0; cc < CNUM; cc++) {
                unsigned long long mask = __ballot(c == cc);
                if (mask == 0ull) continue;
                if (lane == (__ffsll(mask) - 1)) atomicAdd(&h[cc], __popcll(mask));
            }
        }
        __syncthreads();
        if (t < CNUM) counts_part[bid * 16 + t] = h[t];
        return;
    }

    // init block
    for (int i = t; i < CNUM * DH; i += 256) pooled[i] = 0.f;
    if (t < CNUM) a_logit[t] = bc[0];
    if (t < CNUM) scat_pos[t] = 0;
}

// ---------------- dispatch 2: scatter (first) + casts (independent) ----------------
// blocks 0..NSC-1    : scatter (each block redundantly reduces+scans counts_part;
//                      block 0 publishes counts/offsets/tile_off)
// next nxb blocks    : cast x fp32->bf16 (original row order)
// next nw blocks     : transpose+cast W1,W2 -> n-major bf16

__global__ __launch_bounds__(256) void k_scat2(
    const int* __restrict__ cid, int n, const int* __restrict__ counts_part,
    const float* __restrict__ x, const float* __restrict__ W1, const float* __restrict__ W2,
    ushort_t* __restrict__ xb, ushort_t* __restrict__ W1t, ushort_t* __restrict__ W2t,
    int nxb, int nw,
    int* __restrict__ counts, int* __restrict__ offsets, int* __restrict__ tile_off,
    int* __restrict__ scat_pos, int* __restrict__ bucket)
{
    int bid = blockIdx.x;
    int t = threadIdx.x;

    if (bid < NSC) {
        __shared__ int cnts[CNUM], off[CNUM];
        if (t < CNUM) {
            int s = 0;
            #pragma unroll 8
            for (int b = 0; b < NH; b++) s += counts_part[b * 16 + t];
            cnts[t] = s;
        }
        __syncthreads();
        if (t == 0) {
            int a = 0;
            for (int c = 0; c < CNUM; c++) { off[c] = a; a += cnts[c]; }
            if (bid == 0) {
                int aa = 0, tt = 0;
                for (int c = 0; c < CNUM; c++) {
                    offsets[c] = aa; tile_off[c] = tt; counts[c] = cnts[c];
                    aa += cnts[c]; tt += (cnts[c] + 127) >> 7;
                }
                offsets[CNUM] = aa; tile_off[CNUM] = tt;
            }
        }
        __syncthreads();
        int lane = t & 63;
        for (int i = bid * 256 + t; i < n; i += NSC * 256) {
            int c = cid[i];
            #pragma unroll
            for (int cc = 0; cc < CNUM; cc++) {
                unsigned long long mask = __ballot(c == cc);
                if (mask == 0ull) continue;
                int leader = __ffsll(mask) - 1;
                int basep = 0;
                if (lane == leader) basep = atomicAdd(&scat_pos[cc], __popcll(mask));
                basep = __shfl(basep, leader, 64);
                if (c == cc) {
                    int rank = __popcll(mask & ((1ull << lane) - 1ull));
                    bucket[off[cc] + basep + rank] = i;
                }
            }
        }
        return;
    }
    bid -= NSC;

    if (bid < nxb) {
        int row = bid * 2 + (t >> 7);
        if (row >= n) return;
        int col = (t & 127) * 8;
        const float* src = x + (size_t)row * DIN + col;
        float4 v0 = *(const float4*)(src);
        float4 v1 = *(const float4*)(src + 4);
        ushort_t* dst = xb + (size_t)row * DIN + col;
        *(ushort4*)dst = make_ushort4(f2bf(v0.x), f2bf(v0.y), f2bf(v0.z), f2bf(v0.w));
        *(ushort4*)(dst + 4) = make_ushort4(f2bf(v1.x), f2bf(v1.y), f2bf(v1.z), f2bf(v1.w));
        return;
    }
    bid -= nxb;

    if (bid < nw) {
        __shared__ float tile[64][65];
        int z = bid >> 7;
        int kx = (bid & 127) >> 3;
        int ny = bid & 7;
        const float* src; ushort_t* dst; int K;
        if (z < CNUM) { K = DIN; src = W1 + (size_t)z * K * DH; dst = W1t + (size_t)z * DH * K; }
        else          { K = DH;  src = W2 + (size_t)(z - CNUM) * K * DH; dst = W2t + (size_t)(z - CNUM) * DH * K; }
        int k0 = kx * 64;
        if (k0 >= K) return;
        int n0 = ny * 64;
        int rr = t >> 4;
        int cc = (t & 15) * 4;
        #pragma unroll
        for (int i = 0; i < 4; i++) {
            int row = rr + 16 * i;
            float4 v = *(const float4*)(src + (size_t)(k0 + row) * DH + n0 + cc);
            tile[row][cc + 0] = v.x; tile[row][cc + 1] = v.y;
            tile[row][cc + 2] = v.z; tile[row][cc + 3] = v.w;
        }
        __syncthreads();
        #pragma unroll
        for (int i = 0; i < 4; i++) {
            int nrow = rr + 16 * i;
            ushort4 o = make_ushort4(f2bf(tile[cc + 0][nrow]), f2bf(tile[cc + 1][nrow]),
                                     f2bf(tile[cc + 2][nrow]), f2bf(tile[cc + 3][nrow]));
            *(ushort4*)(dst + (size_t)(n0 + nrow) * K + k0 + cc) = o;
        }
    }
}

// ---------------- m97-style grouped GEMM, 128x128 tile, BK=32 ----------------
// grid (4, maxt): x = n-tile (consecutive blocks share the A-tile -> L2 hits).
// C/D: col=lane&15, row=quad*4+reg  [m89/m91].

__device__ inline void gemm_tile(
    const ushort_t* aSrc0, const ushort_t* aSrc1,
    const ushort_t* bSrc0, const ushort_t* bSrc1, int Kd,
    f32x4 acc[4][4], ushort_t As[128][32], ushort_t Bs[128][32])
{
    int t = threadIdx.x;
    int lane = t & 63;
    int w = t >> 6, wr = w >> 1, wc = w & 1;
    int m = lane & 15, quad = lane >> 4;

    int r0 = t >> 2;
    int kc = (t & 3) * 8;

    ushort_t* aDst0 = &As[r0][kc];
    ushort_t* aDst1 = &As[64 + r0][kc];
    ushort_t* bDst0 = &Bs[r0][kc];
    ushort_t* bDst1 = &Bs[64 + r0][kc];

    const ushort_t* aF = &As[64 * wr + m][quad * 8];
    const ushort_t* bF = &Bs[64 * wc + m][quad * 8];

    for (int k0 = 0; k0 < Kd; k0 += 32) {
        __syncthreads();
        gl_lds16(aSrc0 + k0, aDst0);
        gl_lds16(aSrc1 + k0, aDst1);
        gl_lds16(bSrc0 + k0, bDst0);
        gl_lds16(bSrc1 + k0, bDst1);
        __syncthreads();
        bf16x8 a[4], b[4];
        #pragma unroll
        for (int mf = 0; mf < 4; mf++) a[mf] = *(const bf16x8*)(aF + mf * 16 * 32);
        #pragma unroll
        for (int nf = 0; nf < 4; nf++) b[nf] = *(const bf16x8*)(bF + nf * 16 * 32);
        #pragma unroll
        for (int mf = 0; mf < 4; mf++)
            #pragma unroll
            for (int nf = 0; nf < 4; nf++)
                acc[mf][nf] = __builtin_amdgcn_mfma_f32_16x16x32_bf16(a[mf], b[nf], acc[mf][nf], 0, 0, 0);
    }
}

__global__ __launch_bounds__(256, 1) void k_mfma1(
    const ushort_t* __restrict__ xb, const ushort_t* __restrict__ W1t,
    const float* __restrict__ b1, const int* __restrict__ bucket,
    const int* __restrict__ offsets, const int* __restrict__ counts,
    const int* __restrict__ tile_off,
    ushort_t* __restrict__ H1)
{
    __shared__ ushort_t As[128][32];
    __shared__ ushort_t Bs[128][32];
    int tx = blockIdx.y;
    if (tx >= tile_off[CNUM]) return;
    int c = 0;
    while (tx >= tile_off[c + 1]) c++;
    int m0 = (tx - tile_off[c]) * 128;
    int base = offsets[c], cnt = counts[c];
    int tile_n = blockIdx.x * 128;

    int t = threadIdx.x;
    int r0 = t >> 2;
    int kc = (t & 3) * 8;
    int ra0 = m0 + r0;      if (ra0 > cnt - 1) ra0 = cnt - 1; if (ra0 < 0) ra0 = 0;
    int ra1 = m0 + 64 + r0; if (ra1 > cnt - 1) ra1 = cnt - 1; if (ra1 < 0) ra1 = 0;
    const ushort_t* aSrc0 = xb + (size_t)bucket[base + ra0] * DIN + kc;   // indirect gather
    const ushort_t* aSrc1 = xb + (size_t)bucket[base + ra1] * DIN + kc;
    const ushort_t* bSrc0 = W1t + ((size_t)c * DH + tile_n + r0) * DIN + kc;
    const ushort_t* bSrc1 = W1t + ((size_t)c * DH + tile_n + 64 + r0) * DIN + kc;

    f32x4 acc[4][4] = {};
    gemm_tile(aSrc0, aSrc1, bSrc0, bSrc1, DIN, acc, As, Bs);

    int lane = t & 63;
    int w = t >> 6, wr = w >> 1, wc = w & 1;
    int m = lane & 15, quad = lane >> 4;
    int col0 = tile_n + 64 * wc;
    #pragma unroll
    for (int nf = 0; nf < 4; nf++) {
        int col = col0 + 16 * nf + m;
        float bv = b1[c * DH + col];
        #pragma unroll
        for (int mf = 0; mf < 4; mf++) {
            int rowb = m0 + 64 * wr + 16 * mf + quad * 4;
            #pragma unroll
            for (int r = 0; r < 4; r++) {
                int row = rowb + r;
                if (row < cnt)
                    H1[(size_t)(base + row) * DH + col] = f2bf(fmaxf(acc[mf][nf][r] + bv, 0.f));
            }
        }
    }
}

__global__ __launch_bounds__(256, 1) void k_mfma2(
    const ushort_t* __restrict__ H1, const ushort_t* __restrict__ W2t,
    const float* __restrict__ b2,
    const int* __restrict__ offsets, const int* __restrict__ counts,
    const int* __restrict__ tile_off,
    float* __restrict__ pooled)
{
    __shared__ ushort_t As[128][32];
    __shared__ ushort_t Bs[128][32];
    int tx = blockIdx.y;
    if (tx >= tile_off[CNUM]) return;
    int c = 0;
    while (tx >= tile_off[c + 1]) c++;
    int m0 = (tx - tile_off[c]) * 128;
    int base = offsets[c], cnt = counts[c];
    int tile_n = blockIdx.x * 128;

    int t = threadIdx.x;
    int r0 = t >> 2;
    int kc = (t & 3) * 8;
    int ra0 = m0 + r0;      if (ra0 > cnt - 1) ra0 = cnt - 1; if (ra0 < 0) ra0 = 0;
    int ra1 = m0 + 64 + r0; if (ra1 > cnt - 1) ra1 = cnt - 1; if (ra1 < 0) ra1 = 0;
    const ushort_t* aSrc0 = H1 + (size_t)(base + ra0) * DH + kc;
    const ushort_t* aSrc1 = H1 + (size_t)(base + ra1) * DH + kc;
    const ushort_t* bSrc0 = W2t + ((size_t)c * DH + tile_n + r0) * DH + kc;
    const ushort_t* bSrc1 = W2t + ((size_t)c * DH + tile_n + 64 + r0) * DH + kc;

    f32x4 acc[4][4] = {};
    gemm_tile(aSrc0, aSrc1, bSrc0, bSrc1, DH, acc, As, Bs);

    int lane = t & 63;
    int w = t >> 6, wr = w >> 1, wc = w & 1;
    int m = lane & 15, quad = lane >> 4;
    int col0 = tile_n + 64 * wc;
    #pragma unroll
    for (int nf = 0; nf < 4; nf++) {
        int col = col0 + 16 * nf + m;
        float bv = b2[c * DH + col];
        float s = 0.f;
        #pragma unroll
        for (int mf = 0; mf < 4; mf++) {
            int rowb = m0 + 64 * wr + 16 * mf + quad * 4;
            #pragma unroll
            for (int r = 0; r < 4; r++) {
                int row = rowb + r;
                if (row < cnt) s += fmaxf(acc[mf][nf][r] + bv, 0.f);
            }
        }
        s += __shfl_xor(s, 16);
        s += __shfl_xor(s, 32);
        if (quad == 0) atomicAdd(&pooled[c * DH + col], s);
    }
}

// ---------------- parallel epilogue (R7-proven split tail) ----------------

__global__ __launch_bounds__(256) void k_fc2(
    const float* __restrict__ pooled, const int* __restrict__ counts,
    const float* __restrict__ Wfc, const float* __restrict__ bfc,
    float* __restrict__ hfc)
{
    int c = blockIdx.x;
    int c0 = blockIdx.y * 64;
    __shared__ float ps[DH];
    __shared__ float red[4][64];
    int t = threadIdx.x;
    float cnt = fmaxf((float)counts[c], 1.f);
    ps[t] = pooled[c * DH + t] / cnt;
    ps[t + 256] = pooled[c * DH + t + 256] / cnt;
    __syncthreads();
    int col = c0 + (t & 63);
    int ks = t >> 6;
    float acc = 0.f;
    #pragma unroll 8
    for (int k = ks * 128; k < ks * 128 + 128; k++)
        acc = fmaf(ps[k], Wfc[(size_t)k * DH + col], acc);
    red[ks][t & 63] = acc;
    __syncthreads();
    if (t < 64) {
        float v = red[0][t] + red[1][t] + red[2][t] + red[3][t] + bfc[c0 + t];
        hfc[c * DH + c0 + t] = fmaxf(v, 0.f);
    }
}

__global__ __launch_bounds__(256) void k_gate2(
    const float* __restrict__ hfc,
    const float* __restrict__ Wa, const float* __restrict__ ba,
    const float* __restrict__ Wb, const float* __restrict__ bb,
    const float* __restrict__ Wc,
    float* __restrict__ a_logit)
{
    int c = blockIdx.x;
    int d0 = blockIdx.y * 64;
    __shared__ float hf[DH];
    __shared__ float ra[4][64], rb[4][64];
    int t = threadIdx.x;
    hf[t] = hfc[c * DH + t];
    hf[t + 256] = hfc[c * DH + t + 256];
    __syncthreads();
    int d = d0 + (t & 63);
    int ks = t >> 6;
    float ga = 0.f, gb = 0.f;
    #pragma unroll 8
    for (int k = ks * 128; k < ks * 128 + 128; k++) {
        float h = hf[k];
        ga = fmaf(h, Wa[(size_t)k * DATT + d], ga);
        gb = fmaf(h, Wb[(size_t)k * DATT + d], gb);
    }
    ra[ks][t & 63] = ga;
    rb[ks][t & 63] = gb;
    __syncthreads();
    if (t < 64) {
        float sa = ra[0][t] + ra[1][t] + ra[2][t] + ra[3][t] + ba[d0 + t];
        float sb = rb[0][t] + rb[1][t] + rb[2][t] + rb[3][t] + bb[d0 + t];
        float g = tanhf(sa) * (1.f / (1.f + expf(-sb)));
        float p = g * Wc[d0 + t];
        #pragma unroll
        for (int off = 32; off >= 1; off >>= 1) p += __shfl_down(p, off, 64);
        if (t == 0) atomicAdd(&a_logit[c], p);
    }
}

__global__ __launch_bounds__(1024) void k_final(
    const float* __restrict__ hfc, const float* __restrict__ a_logit,
    const float* __restrict__ Wr, const float* __restrict__ br,
    const float* __restrict__ Wcls, const float* __restrict__ bcls,
    float* __restrict__ out)
{
    int t = threadIdx.x;
    __shared__ float hp[DH];
    __shared__ float r1[4][DATT];
    __shared__ float hr[DATT];
    __shared__ float wred[4][NCLS];

    float al[CNUM];
    float m = -1e30f;
    #pragma unroll
    for (int c = 0; c < CNUM; c++) { al[c] = a_logit[c]; m = fmaxf(m, al[c]); }
    float s = 0.f;
    #pragma unroll
    for (int c = 0; c < CNUM; c++) { al[c] = expf(al[c] - m); s += al[c]; }
    float inv = 1.f / s;

    if (t < DH) {
        float v = 0.f;
        #pragma unroll
        for (int c = 0; c < CNUM; c++) v = fmaf(al[c] * inv, hfc[c * DH + t], v);
        hp[t] = v;
    }
    __syncthreads();

    int d = t & 255;
    int ks = t >> 8;
    float acc = 0.f;
    #pragma unroll 8
    for (int k = ks * 128; k < ks * 128 + 128; k++)
        acc = fmaf(hp[k], Wr[(size_t)k * DATT + d], acc);
    r1[ks][d] = acc;
    __syncthreads();
    if (t < DATT)
        hr[t] = fmaxf(r1[0][t] + r1[1][t] + r1[2][t] + r1[3][t] + br[t], 0.f);
    __syncthreads();

    if (t < 256) {
        float h = hr[t];
        #pragma unroll
        for (int cls = 0; cls < NCLS; cls++) {
            float p = h * Wcls[(size_t)t * NCLS + cls];
            #pragma unroll
            for (int off = 32; off >= 1; off >>= 1) p += __shfl_down(p, off, 64);
            if ((t & 63) == 0) wred[t >> 6][cls] = p;
        }
    }
    __syncthreads();
    if (t == 0) {
        float lg[NCLS];
        #pragma unroll
        for (int cls = 0; cls < NCLS; cls++)
            lg[cls] = bcls[cls] + wred[0][cls] + wred[1][cls] + wred[2][cls] + wred[3][cls];
        float mm = lg[0];
        #pragma unroll
        for (int i = 1; i < NCLS; i++) mm = fmaxf(mm, lg[i]);
        float ss = 0.f, pr[NCLS];
        #pragma unroll
        for (int i = 0; i < NCLS; i++) { pr[i] = expf(lg[i] - mm); ss += pr[i]; }
        int am = 0; float best = lg[0];
        #pragma unroll
        for (int i = 1; i < NCLS; i++) if (lg[i] > best) { best = lg[i]; am = i; }
        #pragma unroll
        for (int i = 0; i < NCLS; i++) out[i] = lg[i];
        #pragma unroll
        for (int i = 0; i < NCLS; i++) out[4 + i] = pr[i] / ss;
        out[8] = (float)am;
    }
}

// ---------------- fp32 fallback GEMMs (round-1 proven) ----------------

#define MT 64
#define NT 128
#define KT 32

__global__ __launch_bounds__(256) void k_gemm1(
    const float* __restrict__ x, const float* __restrict__ W1, const float* __restrict__ b1,
    const int* __restrict__ bucket, const int* __restrict__ offsets, const int* __restrict__ counts,
    float* __restrict__ H1)
{
    int c = blockIdx.z;
    int cnt = counts[c];
    int m0 = blockIdx.x * MT;
    if (m0 >= cnt) return;
    int rows = min(MT, cnt - m0);
    int n0 = blockIdx.y * NT;
    int base = offsets[c];

    __shared__ float As[KT][MT + 4];
    __shared__ float Bs[KT][NT];

    int t = threadIdx.x;
    int tr = t >> 4;
    int tc = t & 15;
    int lr = t >> 2;
    int lk = (t & 3) * 8;
    const float* xrow = nullptr;
    if (lr < rows) xrow = x + (size_t)bucket[base + m0 + lr] * DIN;

    float acc[4][8];
    #pragma unroll
    for (int i = 0; i < 4; i++)
        #pragma unroll
        for (int j = 0; j < 8; j++) acc[i][j] = 0.f;

    const float* Wp = W1 + (size_t)c * DIN * DH + n0;

    for (int k0 = 0; k0 < DIN; k0 += KT) {
        __syncthreads();
        if (xrow) {
            float4 v0 = *(const float4*)(xrow + k0 + lk);
            float4 v1 = *(const float4*)(xrow + k0 + lk + 4);
            As[lk + 0][lr] = v0.x; As[lk + 1][lr] = v0.y;
            As[lk + 2][lr] = v0.z; As[lk + 3][lr] = v0.w;
            As[lk + 4][lr] = v1.x; As[lk + 5][lr] = v1.y;
            As[lk + 6][lr] = v1.z; As[lk + 7][lr] = v1.w;
        } else {
            #pragma unroll
            for (int i = 0; i < 8; i++) As[lk + i][lr] = 0.f;
        }
        #pragma unroll
        for (int i = 0; i < 4; i++) {
            int idx = i * 256 + t;
            int kk = idx >> 5;
            int cv = idx & 31;
            *(float4*)&Bs[kk][cv * 4] = *(const float4*)(Wp + (size_t)(k0 + kk) * DH + cv * 4);
        }
        __syncthreads();
        #pragma unroll
        for (int k = 0; k < KT; k++) {
            float4 av  = *(const float4*)&As[k][4 * tr];
            float4 bv0 = *(const float4*)&Bs[k][4 * tc];
            float4 bv1 = *(const float4*)&Bs[k][64 + 4 * tc];
            float a[4] = {av.x, av.y, av.z, av.w};
            float b[8] = {bv0.x, bv0.y, bv0.z, bv0.w, bv1.x, bv1.y, bv1.z, bv1.w};
            #pragma unroll
            for (int i = 0; i < 4; i++)
                #pragma unroll
                for (int j = 0; j < 8; j++)
                    acc[i][j] = fmaf(a[i], b[j], acc[i][j]);
        }
    }

    #pragma unroll
    for (int i = 0; i < 4; i++) {
        int r = 4 * tr + i;
        if (r < rows) {
            size_t grow = (size_t)(base + m0 + r) * DH;
            #pragma unroll
            for (int j = 0; j < 8; j++) {
                int cidx = (j < 4) ? (4 * tc + j) : (64 + 4 * tc + (j - 4));
                int col = n0 + cidx;
                float v = acc[i][j] + b1[c * DH + col];
                H1[grow + col] = fmaxf(v, 0.f);
            }
        }
    }
}

__global__ __launch_bounds__(256) void k_gemm2(
    const float* __restrict__ H1, const float* __restrict__ W2, const float* __restrict__ b2,
    const int* __restrict__ offsets, const int* __restrict__ counts,
    float* __restrict__ pooled)
{
    int c = blockIdx.z;
    int cnt = counts[c];
    int m0 = blockIdx.x * MT;
    if (m0 >= cnt) return;
    int rows = min(MT, cnt - m0);
    int n0 = blockIdx.y * NT;
    int base = offsets[c];

    __shared__ float As[KT][MT + 4];
    __shared__ float Bs[KT][NT];
    __shared__ float red[16][NT];

    int t = threadIdx.x;
    int tr = t >> 4;
    int tc = t & 15;
    int lr = t >> 2;
    int lk = (t & 3) * 8;
    const float* arow = (lr < rows) ? (H1 + (size_t)(base + m0 + lr) * DH) : nullptr;

    float acc[4][8];
    #pragma unroll
    for (int i = 0; i < 4; i++)
        #pragma unroll
        for (int j = 0; j < 8; j++) acc[i][j] = 0.f;

    const float* Wp = W2 + (size_t)c * DH * DH + n0;

    for (int k0 = 0; k0 < DH; k0 += KT) {
        __syncthreads();
        if (arow) {
            float4 v0 = *(const float4*)(arow + k0 + lk);
            float4 v1 = *(const float4*)(arow + k0 + lk + 4);
            As[lk + 0][lr] = v0.x; As[lk + 1][lr] = v0.y;
            As[lk + 2][lr] = v0.z; As[lk + 3][lr] = v0.w;
            As[lk + 4][lr] = v1.x; As[lk + 5][lr] = v1.y;
            As[lk + 6][lr] = v1.z; As[lk + 7][lr] = v1.w;
        } else {
            #pragma unroll
            for (int i = 0; i < 8; i++) As[lk + i][lr] = 0.f;
        }
        #pragma unroll
        for (int i = 0; i < 4; i++) {
            int idx = i * 256 + t;
            int kk = idx >> 5;
            int cv = idx & 31;
            *(float4*)&Bs[kk][cv * 4] = *(const float4*)(Wp + (size_t)(k0 + kk) * DH + cv * 4);
        }
        __syncthreads();
        #pragma unroll
        for (int k = 0; k < KT; k++) {
            float4 av  = *(const float4*)&As[k][4 * tr];
            float4 bv0 = *(const float4*)&Bs[k][4 * tc];
            float4 bv1 = *(const float4*)&Bs[k][64 + 4 * tc];
            float a[4] = {av.x, av.y, av.z, av.w};
            float b[8] = {bv0.x, bv0.y, bv0.z, bv0.w, bv1.x, bv1.y, bv1.z, bv1.w};
            #pragma unroll
            for (int i = 0; i < 4; i++)
                #pragma unroll
                for (int j = 0; j < 8; j++)
                    acc[i][j] = fmaf(a[i], b[j], acc[i][j]);
        }
    }

    __syncthreads();
    #pragma unroll
    for (int j = 0; j < 8; j++) {
        int cidx = (j < 4) ? (4 * tc + j) : (64 + 4 * tc + (j - 4));
        float bias = b2[c * DH + n0 + cidx];
        float s = 0.f;
        #pragma unroll
        for (int i = 0; i < 4; i++) {
            if (4 * tr + i < rows) s += fmaxf(acc[i][j] + bias, 0.f);
        }
        red[tr][cidx] = s;
    }
    __syncthreads();
    if (t < NT) {
        float s = 0.f;
        #pragma unroll
        for (int r = 0; r < 16; r++) s += red[r][t];
        atomicAdd(&pooled[c * DH + n0 + t], s);
    }
}

// ---------------- launcher ----------------

extern "C" void kernel_launch(void* const* d_in, const int* in_sizes, int n_in,
                              void* d_out, int out_size, void* d_ws, size_t ws_size,
                              hipStream_t stream) {
    (void)n_in; (void)out_size;
    const float* x    = (const float*)d_in[0];
    const int*   cid  = (const int*)d_in[1];
    const float* W1   = (const float*)d_in[2];
    const float* b1   = (const float*)d_in[3];
    const float* W2   = (const float*)d_in[4];
    const float* b2   = (const float*)d_in[5];
    const float* Wfc  = (const float*)d_in[6];
    const float* bfc  = (const float*)d_in[7];
    const float* Wa   = (const float*)d_in[8];
    const float* ba   = (const float*)d_in[9];
    const float* Wb   = (const float*)d_in[10];
    const float* bb   = (const float*)d_in[11];
    const float* Wc   = (const float*)d_in[12];
    const float* bc   = (const float*)d_in[13];
    const float* Wr   = (const float*)d_in[14];
    const float* br   = (const float*)d_in[15];
    const float* Wcls = (const float*)d_in[16];
    const float* bcls = (const float*)d_in[17];
    float* out = (float*)d_out;
    float* ws  = (float*)d_ws;

    int n = in_sizes[1];

    float* pooled     = ws + 0;                  // 5120
    int*   counts     = (int*)(ws + 5120);       // 16
    int*   offsets    = (int*)(ws + 5136);       // 16
    int*   tile_off   = (int*)(ws + 5152);       // 16
    float* a_logit    = ws + 5168;               // 16
    int*   scat_pos   = (int*)(ws + 5184);       // 16
    float* hfc        = ws + 5200;               // 5120 -> 10320
    int*   counts_part= (int*)(ws + 10320);      // 1024 -> 11344
    int*   bucket     = (int*)(ws + 11344);      // n

    size_t big0 = (((size_t)(11344 + n) * 4) + 255) & ~(size_t)255;
    size_t w1t_bytes = (size_t)CNUM * DH * DIN * 2;
    size_t w2t_bytes = (size_t)CNUM * DH * DH * 2;
    size_t h1_bytes  = (size_t)n * DH * 2;
    size_t xb_bytes  = (size_t)n * DIN * 2;
    size_t need = big0 + w1t_bytes + w2t_bytes + h1_bytes + xb_bytes;

    ushort_t* W1t = (ushort_t*)((char*)d_ws + big0);
    ushort_t* W2t = (ushort_t*)((char*)d_ws + big0 + w1t_bytes);
    ushort_t* H1  = (ushort_t*)((char*)d_ws + big0 + w1t_bytes + w2t_bytes);
    ushort_t* xb  = (ushort_t*)((char*)d_ws + big0 + w1t_bytes + w2t_bytes + h1_bytes);

    int fast = (ws_size >= need) ? 1 : 0;
    int nxb = fast ? (n + 1) / 2 : 0;
    int nw  = fast ? 128 * 2 * CNUM : 0;

    k_hist<<<NH + 1, 256, 0, stream>>>(cid, n, bc, counts_part, pooled, a_logit, scat_pos);
    k_scat2<<<NSC + nxb + nw, 256, 0, stream>>>(
        cid, n, counts_part, x, W1, W2, xb, W1t, W2t, nxb, nw,
        counts, offsets, tile_off, scat_pos, bucket);

    if (fast) {
        int maxt = n / 128 + CNUM;
        k_mfma1<<<dim3(4, maxt), 256, 0, stream>>>(xb, W1t, b1, bucket, offsets, counts, tile_off, H1);
        k_mfma2<<<dim3(4, maxt), 256, 0, stream>>>(H1, W2t, b2, offsets, counts, tile_off, pooled);
    } else {
        float* H1f = ws + ((11344 + n + 31) & ~31);
        dim3 gg((n + MT - 1) / MT, DH / NT, CNUM);
        k_gemm1<<<gg, 256, 0, stream>>>(x, W1, b1, bucket, offsets, counts, H1f);
        k_gemm2<<<gg, 256, 0, stream>>>(H1f, W2, b2, offsets, counts, pooled);
    }

    k_fc2<<<dim3(CNUM, 8), 256, 0, stream>>>(pooled, counts, Wfc, bfc, hfc);
    k_gate2<<<dim3(CNUM, 4), 256, 0, stream>>>(hfc, Wa, ba, Wb, bb, Wc, a_logit);
    k_final<<<1, 1024, 0, stream>>>(hfc, a_logit, Wr, br, Wcls, bcls, out);
}